// Round 5
// baseline (2233.993 us; speedup 1.0000x reference)
//
#include <hip/hip_runtime.h>

// VectorQuantizer: z (32,64,64,64) fp32, embedding_w (2048,64) fp32.
// Outputs concat: quantized_out (32,64,64,64) | indices (32,64,64) as float | loss (1)
//
// Numerics: bit-exact replication of the numpy fp32 reference (verified R1-R4, absmax 0):
//   S_n = pairwise64(z_n^2), b_k = pairwise64(w_k^2)  (numpy pairwise_sum order)
//   C_nk = one sequential fp32 FMA chain over c=0..63 ascending per (n,k)
//   d = fp32(fp32(S + b) - fp32(2*C)), argmin first-index tie-break.
//
// R5 vs R4: w moved from the scalar path (s_load, shared lgkmcnt with ds_read,
// forced lgkmcnt(0) drains, SGPR splats cost v_movs) to the vector path:
// global_load_dwordx4 at an address made opaque-non-uniform (inline v_mov 0),
// double-buffered in VGPRs one c0-step ahead (vmcnt pipelining). Splats now
// VGPR-sourced -> op_sel splat-fold into v_pk_fma_f32. z stays in LDS as
// row-pairs (float2); packing is across rows only, so each (n,k) chain remains
// the same sequential fp32 fmaf chain (bit-exact). Argmin merge + epilogue
// identical to R4 (verified).

#define KCODES   2048
#define CDIM     64
#define OUT_Q    0
#define OUT_IDX  8388608
#define OUT_LOSS 8519680
#define PSTR     132        // floats per pair-row: 64 dims * 2 + 4 pad

typedef float f2 __attribute__((ext_vector_type(2)));

__device__ __forceinline__ f2 fma2(f2 a, f2 b, f2 c) {
#if __has_builtin(__builtin_elementwise_fma)
    return __builtin_elementwise_fma(a, b, c);
#else
    f2 r; r.x = __builtin_fmaf(a.x, b.x, c.x); r.y = __builtin_fmaf(a.y, b.y, c.y);
    return r;
#endif
}

__device__ __forceinline__ float pairwise64(const float a[64]) {
    float r[8];
#pragma unroll
    for (int j = 0; j < 8; ++j) r[j] = a[j];
#pragma unroll
    for (int m = 1; m < 8; ++m)
#pragma unroll
        for (int j = 0; j < 8; ++j) r[j] = __fadd_rn(r[j], a[m * 8 + j]);
    float s01 = __fadd_rn(r[0], r[1]);
    float s23 = __fadd_rn(r[2], r[3]);
    float s45 = __fadd_rn(r[4], r[5]);
    float s67 = __fadd_rn(r[6], r[7]);
    return __fadd_rn(__fadd_rn(s01, s23), __fadd_rn(s45, s67));
}

__device__ __forceinline__ float fc(const float4& v, int i) {
    return i == 0 ? v.x : (i == 1 ? v.y : (i == 2 ? v.z : v.w));
}

// ---------------- kernel A: b_k = pairwise64(w_k^2) ----------------
__global__ __launch_bounds__(256) void vq_bsum(const float* __restrict__ w,
                                               float* __restrict__ bsum) {
    int k = blockIdx.x * 256 + threadIdx.x;
    const float4* wr = (const float4*)(w + (size_t)k * CDIM);
    float a[64];
#pragma unroll
    for (int m = 0; m < 16; ++m) {
        float4 v = wr[m];
        a[4 * m + 0] = __fmul_rn(v.x, v.x);
        a[4 * m + 1] = __fmul_rn(v.y, v.y);
        a[4 * m + 2] = __fmul_rn(v.z, v.z);
        a[4 * m + 3] = __fmul_rn(v.w, v.w);
    }
    bsum[k] = pairwise64(a);
}

// ---------------- kernel B: main VQ (fused argmin + epilogue) ----------------
__global__ __launch_bounds__(256, 2) void vq_main(const float* __restrict__ z,
                                                  const float* __restrict__ w,
                                                  const float* __restrict__ bsum,
                                                  float* __restrict__ out,
                                                  float* __restrict__ partial) {
    __shared__ float zsh[128 * PSTR];               // 67.6 KB: zsh[pair][dim] as float2
    __shared__ float Ss[256];
    __shared__ unsigned long long skey[256];
    __shared__ double lred[4];

    const int t  = threadIdx.x;
    const int l  = t & 63;                          // lane
    const int bb = blockIdx.x;                      // 0..511; rows [bb*256, bb*256+256)
    const size_t zbase = (size_t)(bb >> 4) * 262144 + (size_t)(bb & 15) * 256;

    // ---- stage z tile: zsh[p][c] = (z_row{2p}_c, z_row{2p+1}_c) ----
#pragma unroll
    for (int m = 0; m < 32; ++m) {
        int i = m * 256 + t;                        // 0..8191
        int p = i & 127;
        int c = i >> 7;
        f2 v = *(const f2*)(z + zbase + (size_t)c * 4096 + 2 * p);
        *(f2*)&zsh[p * PSTR + 2 * c] = v;
    }
    __syncthreads();

    // ---- S per row (numpy pairwise of squares); init argmin keys ----
    {
        float a[64];
        const int pb = (t >> 1) * PSTR + (t & 1);
#pragma unroll
        for (int c = 0; c < 64; ++c) {
            float v = zsh[pb + 2 * c];
            a[c] = __fmul_rn(v, v);
        }
        Ss[t] = pairwise64(a);
        skey[t] = 0xFFFFFFFFFFFFFFFFull;
    }
    __syncthreads();

    f2 Sp0, Sp1;
    Sp0.x = Ss[2 * l];       Sp0.y = Ss[2 * l + 1];
    Sp1.x = Ss[2 * l + 128]; Sp1.y = Ss[2 * l + 129];

    // wave-uniform code range: wave wv handles codes [wv*512, wv*512+512)
    const int kwave = __builtin_amdgcn_readfirstlane(t >> 6) * 512;

    // opaque VGPR zero: prevents the compiler from proving w addresses
    // wave-uniform, forcing global_load (vmcnt path) instead of s_load
    int vzero;
    asm("v_mov_b32 %0, 0" : "=v"(vzero));
    const float* wv_ = w + (size_t)kwave * CDIM + vzero;

    float dmin0 = __builtin_inff(), dmin1 = dmin0, dmin2 = dmin0, dmin3 = dmin0;
    int   kmin0 = 0, kmin1 = 0, kmin2 = 0, kmin3 = 0;

    const int zoffA = l * PSTR;
    const int zoffB = (l + 64) * PSTR;

    // ---- w double buffer: 2 x 8 codes x float4 (one c0-step of dims) ----
    float4 wbuf[2][8];
#pragma unroll
    for (int j = 0; j < 8; ++j)
        wbuf[0][j] = *(const float4*)(wv_ + j * CDIM);      // (ks=0, c0=0)

    for (int ks = 0; ks < 64; ++ks) {
        const int k0 = kwave + ks * 8;

        f2 acc0[8], acc1[8];
#pragma unroll
        for (int j = 0; j < 8; ++j) { acc0[j] = (f2)0.f; acc1[j] = (f2)0.f; }

#pragma unroll
        for (int st = 0; st < 16; ++st) {
            const int cur = st & 1, nxt = cur ^ 1;
            const int c0  = st * 4;

            // prefetch next step's w (next c0, or next ks's c0=0, or dummy)
            int noff;
            if (st < 15)       noff = ks * (8 * CDIM) + (st + 1) * 4;
            else if (ks < 63)  noff = (ks + 1) * (8 * CDIM);
            else               noff = 0;                    // dummy, in-bounds
#pragma unroll
            for (int j = 0; j < 8; ++j)
                wbuf[nxt][j] = *(const float4*)(wv_ + noff + j * CDIM);

            // z row-pairs, dims c0..c0+3 (x,y = dim c; z,w = dim c+1)
            float4 a0 = *(const float4*)&zsh[zoffA + 2 * c0];
            float4 a1 = *(const float4*)&zsh[zoffA + 2 * c0 + 4];
            float4 b0 = *(const float4*)&zsh[zoffB + 2 * c0];
            float4 b1 = *(const float4*)&zsh[zoffB + 2 * c0 + 4];
            f2 aL0; aL0.x = a0.x; aL0.y = a0.y;
            f2 aH0; aH0.x = a0.z; aH0.y = a0.w;
            f2 aL1; aL1.x = a1.x; aL1.y = a1.y;
            f2 aH1; aH1.x = a1.z; aH1.y = a1.w;
            f2 bL0; bL0.x = b0.x; bL0.y = b0.y;
            f2 bH0; bH0.x = b0.z; bH0.y = b0.w;
            f2 bL1; bL1.x = b1.x; bL1.y = b1.y;
            f2 bH1; bH1.x = b1.z; bH1.y = b1.w;

#pragma unroll
            for (int j = 0; j < 8; ++j) {
                const float4 wc = wbuf[cur][j];
                f2 w0 = (f2)(wc.x);                 // VGPR splat -> op_sel fold
                f2 w1 = (f2)(wc.y);
                f2 w2 = (f2)(wc.z);
                f2 w3 = (f2)(wc.w);
                // dims ascending -> sequential chain per (row, code), bit-exact
                acc0[j] = fma2(aL0, w0, acc0[j]);
                acc0[j] = fma2(aH0, w1, acc0[j]);
                acc0[j] = fma2(aL1, w2, acc0[j]);
                acc0[j] = fma2(aH1, w3, acc0[j]);
                acc1[j] = fma2(bL0, w0, acc1[j]);
                acc1[j] = fma2(bH0, w1, acc1[j]);
                acc1[j] = fma2(bL1, w2, acc1[j]);
                acc1[j] = fma2(bH1, w3, acc1[j]);
            }
        }

        // d = fp32((S + b) - 2*C); strict < keeps earliest k (k ascending)
        const float4 bq0 = *(const float4*)(bsum + k0);      // uniform -> s_load
        const float4 bq1 = *(const float4*)(bsum + k0 + 4);
#pragma unroll
        for (int j = 0; j < 8; ++j) {
            float bj = j < 4 ? fc(bq0, j) : fc(bq1, j - 4);
            f2 bb2 = (f2)(bj);
            f2 dA = (Sp0 + bb2) - (acc0[j] + acc0[j]);
            f2 dB = (Sp1 + bb2) - (acc1[j] + acc1[j]);
            int kg = k0 + j;
            if (dA.x < dmin0) { dmin0 = dA.x; kmin0 = kg; }
            if (dA.y < dmin1) { dmin1 = dA.y; kmin1 = kg; }
            if (dB.x < dmin2) { dmin2 = dB.x; kmin2 = kg; }
            if (dB.y < dmin3) { dmin3 = dB.y; kmin3 = kg; }
        }
    }

    // ---- merge per-row argmin across the 4 waves (packed key, LDS atomic) ----
    atomicMin(&skey[2 * l],       ((unsigned long long)__float_as_uint(dmin0) << 32) | (unsigned int)kmin0);
    atomicMin(&skey[2 * l + 1],   ((unsigned long long)__float_as_uint(dmin1) << 32) | (unsigned int)kmin1);
    atomicMin(&skey[2 * l + 128], ((unsigned long long)__float_as_uint(dmin2) << 32) | (unsigned int)kmin2);
    atomicMin(&skey[2 * l + 129], ((unsigned long long)__float_as_uint(dmin3) << 32) | (unsigned int)kmin3);
    __syncthreads();

    // ---- epilogue: thread t owns row t ----
    const int kq = (int)(skey[t] & 0xFFFFFFFFull);
    out[OUT_IDX + (size_t)bb * 256 + t] = (float)kq;

    const float* wq = w + (size_t)kq * CDIM;
    const int pb = (t >> 1) * PSTR + (t & 1);
    double lacc = 0.0;
#pragma unroll
    for (int c = 0; c < 64; ++c) {
        float zv = zsh[pb + 2 * c];
        float q  = wq[c];
        float d1  = __fsub_rn(q, zv);               // quantized - zp
        float val = __fadd_rn(zv, d1);              // zp + (q - zp)
        out[OUT_Q + zbase + (size_t)c * 4096 + t] = val;
        lacc += (double)__fmul_rn(d1, d1);
    }

#pragma unroll
    for (int off = 1; off < 64; off <<= 1) lacc += __shfl_xor(lacc, off, 64);
    if ((t & 63) == 0) lred[t >> 6] = lacc;
    __syncthreads();
    if (t == 0) {
        double tot = lred[0] + lred[1] + lred[2] + lred[3];
        partial[bb] = (float)(tot * (0.25 / 8388608.0));
    }
}

// ---------------- kernel C: reduce loss partials (512) ----------------
__global__ __launch_bounds__(256) void vq_loss(const float* __restrict__ partial,
                                               float* __restrict__ out) {
    int t = threadIdx.x;
    double s = (double)partial[t] + (double)partial[t + 256];
#pragma unroll
    for (int off = 1; off < 64; off <<= 1) s += __shfl_xor(s, off, 64);
    __shared__ double sr[4];
    if ((t & 63) == 0) sr[t >> 6] = s;
    __syncthreads();
    if (t == 0) out[OUT_LOSS] = (float)(sr[0] + sr[1] + sr[2] + sr[3]);
}

extern "C" void kernel_launch(void* const* d_in, const int* in_sizes, int n_in,
                              void* d_out, int out_size, void* d_ws, size_t ws_size,
                              hipStream_t stream) {
    (void)in_sizes; (void)n_in; (void)out_size; (void)ws_size;
    const float* z = (const float*)d_in[0];
    const float* w = (const float*)d_in[1];
    float* out     = (float*)d_out;

    float* bsum    = (float*)d_ws;                  // 2048 floats
    float* partial = bsum + KCODES;                 // 512 floats

    vq_bsum<<<8, 256, 0, stream>>>(w, bsum);
    vq_main<<<512, 256, 0, stream>>>(z, w, bsum, out, partial);
    vq_loss<<<1, 256, 0, stream>>>(partial, out);
}